// Round 2
// baseline (4437.832 us; speedup 1.0000x reference)
//
#include <hip/hip_runtime.h>
#include <math.h>

#define N_NEU    2048
#define BB       64
#define TT       100
#define KIN      784
#define NIN_NEU  1024
#define N_OUT    10
#define NOUT_NEU 128
#define SPLITS   8

// ---------------- prep ----------------
__global__ void k_prep(const float* __restrict__ tau, double* __restrict__ d_syn,
                       double* __restrict__ e_tau, int* __restrict__ inv){
    int n = blockIdx.x * blockDim.x + threadIdx.x;
    if(n < N_NEU){
        double tv = (double)tau[n];
        d_syn[n] = exp(-1.0 / tv);
        e_tau[n] = 2.718281828459045 / tv;   // np.e / tau
        inv[n] = -1;
    }
}

__global__ void k_scatter(const int* __restrict__ idx, int* __restrict__ inv){
    int j = blockIdx.x * blockDim.x + threadIdx.x;
    if(j < NIN_NEU) inv[idx[j]] = j;
}

__global__ void k_init(double* v, double* psc, double* rise, double* asc,
                       double* refr, double* spk, double* cnt){
    int i = blockIdx.x * blockDim.x + threadIdx.x;
    if(i < BB * N_NEU){
        v[i] = -60.0; psc[i] = 0.0; rise[i] = 0.0; asc[i] = 0.0;
        refr[i] = 0.0; spk[i] = 0.0; cnt[i] = 0.0;
    }
}

// ---------------- input projection GEMM (fp64 accum from fp32) ----------------
// proj[r][c] = sum_k X[r][k] * Win[c][k],  r in [0,6400), c in [0,1024), k in [0,784)
__global__ __launch_bounds__(256) void k_proj(const float* __restrict__ X, const float* __restrict__ Win,
                                              double* __restrict__ proj){
    __shared__ double As[32][65];
    __shared__ double Bs[32][65];
    const int r0 = blockIdx.x * 64;
    const int c0 = blockIdx.y * 64;
    const int t  = threadIdx.x;
    const int lr = t >> 2;          // 0..63
    const int lk = (t & 3) * 8;     // 0,8,16,24
    const int tx = t & 15, ty = t >> 4;
    double acc[4][4] = {};
    for(int k0 = 0; k0 < KIN; k0 += 32){
        int kk = k0 + lk;
        double a8[8], b8[8];
        if(kk + 8 <= KIN){
            const float* pa = X   + (size_t)(r0+lr)*KIN + kk;
            const float* pb = Win + (size_t)(c0+lr)*KIN + kk;
            float4 ra0 = *reinterpret_cast<const float4*>(pa);
            float4 ra1 = *reinterpret_cast<const float4*>(pa + 4);
            float4 rb0 = *reinterpret_cast<const float4*>(pb);
            float4 rb1 = *reinterpret_cast<const float4*>(pb + 4);
            a8[0]=ra0.x; a8[1]=ra0.y; a8[2]=ra0.z; a8[3]=ra0.w;
            a8[4]=ra1.x; a8[5]=ra1.y; a8[6]=ra1.z; a8[7]=ra1.w;
            b8[0]=rb0.x; b8[1]=rb0.y; b8[2]=rb0.z; b8[3]=rb0.w;
            b8[4]=rb1.x; b8[5]=rb1.y; b8[6]=rb1.z; b8[7]=rb1.w;
        } else {
            #pragma unroll
            for(int e=0;e<8;e++){ a8[e]=0.0; b8[e]=0.0; }
        }
        #pragma unroll
        for(int e=0;e<8;e++){ As[lk+e][lr] = a8[e]; Bs[lk+e][lr] = b8[e]; }
        __syncthreads();
        #pragma unroll
        for(int kkk=0;kkk<32;kkk++){
            double a[4], b[4];
            #pragma unroll
            for(int i=0;i<4;i++) a[i] = As[kkk][ty*4+i];
            #pragma unroll
            for(int j=0;j<4;j++) b[j] = Bs[kkk][tx*4+j];
            #pragma unroll
            for(int i=0;i<4;i++)
                #pragma unroll
                for(int j=0;j<4;j++)
                    acc[i][j] += a[i]*b[j];
        }
        __syncthreads();
    }
    #pragma unroll
    for(int i=0;i<4;i++)
        #pragma unroll
        for(int j=0;j<4;j++)
            proj[(size_t)(r0 + ty*4 + i)*NIN_NEU + c0 + tx*4 + j] = acc[i][j];
}

// ---------------- recurrent GEMM (split-K, fp64 accum, fp32 W, fp64 spk) ----------------
// Ipart[s][b][n] = sum_{m in chunk s} spk[b][m] * Wrec[n][m]
__global__ __launch_bounds__(256) void k_rec(const double* __restrict__ spk, const float* __restrict__ Wrec,
                                             double* __restrict__ Ipart){
    __shared__ double As[32][65];   // [kk][b]
    __shared__ double Bs[32][65];   // [kk][n]
    const int n0 = blockIdx.x * 64;
    const int s  = blockIdx.y;
    const int t  = threadIdx.x;
    const int lr = t >> 2;
    const int lk = (t & 3) * 8;
    const int tx = t & 15, ty = t >> 4;
    double acc[4][4] = {};
    const int kbeg = s * (N_NEU / SPLITS);
    for(int k0 = kbeg; k0 < kbeg + N_NEU/SPLITS; k0 += 32){
        const double* pa = spk + (size_t)lr * N_NEU + k0 + lk;
        double2 a0 = *reinterpret_cast<const double2*>(pa+0);
        double2 a1 = *reinterpret_cast<const double2*>(pa+2);
        double2 a2 = *reinterpret_cast<const double2*>(pa+4);
        double2 a3 = *reinterpret_cast<const double2*>(pa+6);
        const float* pb = Wrec + (size_t)(n0+lr)*N_NEU + k0 + lk;
        float4 rb0 = *reinterpret_cast<const float4*>(pb);
        float4 rb1 = *reinterpret_cast<const float4*>(pb + 4);
        As[lk+0][lr]=a0.x; As[lk+1][lr]=a0.y; As[lk+2][lr]=a1.x; As[lk+3][lr]=a1.y;
        As[lk+4][lr]=a2.x; As[lk+5][lr]=a2.y; As[lk+6][lr]=a3.x; As[lk+7][lr]=a3.y;
        Bs[lk+0][lr]=rb0.x; Bs[lk+1][lr]=rb0.y; Bs[lk+2][lr]=rb0.z; Bs[lk+3][lr]=rb0.w;
        Bs[lk+4][lr]=rb1.x; Bs[lk+5][lr]=rb1.y; Bs[lk+6][lr]=rb1.z; Bs[lk+7][lr]=rb1.w;
        __syncthreads();
        #pragma unroll
        for(int kkk=0;kkk<32;kkk++){
            double a[4], b[4];
            #pragma unroll
            for(int i=0;i<4;i++) a[i] = As[kkk][ty*4+i];
            #pragma unroll
            for(int j=0;j<4;j++) b[j] = Bs[kkk][tx*4+j];
            #pragma unroll
            for(int i=0;i<4;i++)
                #pragma unroll
                for(int j=0;j<4;j++)
                    acc[i][j] += a[i]*b[j];
        }
        __syncthreads();
    }
    double* outp = Ipart + (size_t)s * BB * N_NEU;
    #pragma unroll
    for(int i=0;i<4;i++)
        #pragma unroll
        for(int j=0;j<4;j++)
            outp[(size_t)(ty*4 + i)*N_NEU + n0 + tx*4 + j] = acc[i][j];
}

// ---------------- per-step neuron update ----------------
__global__ __launch_bounds__(256) void k_update(int t,
        const double* __restrict__ proj, const double* __restrict__ Ipart,
        const double* __restrict__ d_syn, const double* __restrict__ e_tau,
        const int* __restrict__ inv,
        double* __restrict__ v, double* __restrict__ psc, double* __restrict__ rise,
        double* __restrict__ asc, double* __restrict__ refr, double* __restrict__ spk,
        double* __restrict__ cnt){
    int i = blockIdx.x * blockDim.x + threadIdx.x;   // i = b*N + n
    if(i >= BB * N_NEU) return;
    int n = i & (N_NEU - 1);
    int b = i >> 11;

    double I = 0.0;
    #pragma unroll
    for(int s=0;s<SPLITS;s++) I += Ipart[(size_t)s*BB*N_NEU + i];
    int j = inv[n];
    if(j >= 0) I += proj[((size_t)t*BB + b)*NIN_NEU + j];

    const double ds = d_syn[n], et = e_tau[n];
    const double dasc = exp(-0.0125);        // exp(-K_ASC*DT)
    double pscv = psc[i], risev = rise[i], ascv = asc[i];
    double refv = refr[i], vv = v[i], sp = spk[i];

    double psc_n  = ds * (pscv + risev);     // DT=1
    double rise_n = ds * risev + et * I;
    double asc_n  = dasc * ascv + (-0.2) * sp;
    double active = (refv <= 0.0) ? 1.0 : 0.0;
    double dv  = (psc_n + asc_n + 0.12) / 2.0 - (vv - (-60.0)) / 20.0;
    double v_n = vv + active * dv;           // active*DT*dv, DT=1
    double x   = v_n - (-45.0);              // v_n - V_TH
    double spk_n = (x >= 0.0) ? active : 0.0;
    v_n = v_n - spk_n * 15.0;                // (V_TH - V_RESET) = 15
    double ref_n = (spk_n > 0.0) ? 2.0 : fmax(refv - 1.0, 0.0);

    v[i] = v_n; psc[i] = psc_n; rise[i] = rise_n; asc[i] = asc_n;
    refr[i] = ref_n; spk[i] = spk_n;
    cnt[i] += spk_n;
}

// ---------------- readout ----------------
__global__ void k_final(const double* __restrict__ cnt, const int* __restrict__ oidx,
                        const float* __restrict__ Wout, float* __restrict__ out){
    int i = blockIdx.x * blockDim.x + threadIdx.x;   // i = b*10 + o
    if(i >= BB * N_OUT) return;
    int b = i / N_OUT, o = i - b * N_OUT;
    double accv = 0.0;
    for(int j=0;j<NOUT_NEU;j++){
        double rate = cnt[(size_t)b*N_NEU + oidx[j]] / 100.0;
        accv += rate * (double)Wout[o*NOUT_NEU + j];
    }
    out[i] = (float)accv;
}

extern "C" void kernel_launch(void* const* d_in, const int* in_sizes, int n_in,
                              void* d_out, int out_size, void* d_ws, size_t ws_size,
                              hipStream_t stream){
    const float* X    = (const float*)d_in[0];
    const float* Win  = (const float*)d_in[1];
    const float* Wrec = (const float*)d_in[2];
    const float* Wout = (const float*)d_in[3];
    const float* tau  = (const float*)d_in[4];
    const int*   iidx = (const int*)d_in[5];
    const int*   oidx = (const int*)d_in[6];
    float* out = (float*)d_out;

    char* w = (char*)d_ws;
    const size_t SZ_PROJ = (size_t)TT*BB*NIN_NEU*sizeof(double);   // 52,428,800
    const size_t SZ_BN   = (size_t)BB*N_NEU*sizeof(double);        // 1,048,576
    double* proj  = (double*)(w);
    double* v     = (double*)(w + SZ_PROJ);
    double* psc   = (double*)(w + SZ_PROJ + 1*SZ_BN);
    double* rise  = (double*)(w + SZ_PROJ + 2*SZ_BN);
    double* asc   = (double*)(w + SZ_PROJ + 3*SZ_BN);
    double* refr  = (double*)(w + SZ_PROJ + 4*SZ_BN);
    double* spk   = (double*)(w + SZ_PROJ + 5*SZ_BN);
    double* cnt   = (double*)(w + SZ_PROJ + 6*SZ_BN);
    double* Ipart = (double*)(w + SZ_PROJ + 7*SZ_BN);
    double* dsyn  = (double*)(w + SZ_PROJ + (7+SPLITS)*SZ_BN);
    double* etau  = dsyn + N_NEU;
    int*    inv   = (int*)(etau + N_NEU);

    k_prep   <<<dim3(8),        dim3(256), 0, stream>>>(tau, dsyn, etau, inv);
    k_scatter<<<dim3(4),        dim3(256), 0, stream>>>(iidx, inv);
    k_init   <<<dim3(512),      dim3(256), 0, stream>>>(v, psc, rise, asc, refr, spk, cnt);
    k_proj   <<<dim3(100,16),   dim3(256), 0, stream>>>(X, Win, proj);
    for(int t=0;t<TT;t++){
        k_rec   <<<dim3(32,SPLITS), dim3(256), 0, stream>>>(spk, Wrec, Ipart);
        k_update<<<dim3(512),       dim3(256), 0, stream>>>(t, proj, Ipart, dsyn, etau, inv,
                                                            v, psc, rise, asc, refr, spk, cnt);
    }
    k_final<<<dim3(3), dim3(256), 0, stream>>>(cnt, oidx, Wout, out);
}